// Round 15
// baseline (2390.126 us; speedup 1.0000x reference)
//
#include <hip/hip_runtime.h>
#include <hip/hip_bf16.h>
#include <cmath>

// Problem constants: B=32, T=1024, J=1024, H=2048
#define BB 32
#define TT 1024
#define JJ 1024
#define HH 2048
#define MM (BB * TT)      // 32768 rows
#define MHALF (MM / 2)    // 16384

typedef short s8v __attribute__((ext_vector_type(8)));   // 8 bf16 raw
typedef float f4v __attribute__((ext_vector_type(4)));
typedef unsigned int u4v __attribute__((ext_vector_type(4)));
union ABu { u4v u; s8v v; };

// ============ exact f32 -> bf16 hi/mid/lo (w == h+m+l exactly) ============
__device__ inline void split_bf16x3(float w, unsigned short& h,
                                    unsigned short& m, unsigned short& l) {
    __hip_bfloat16 bh = __float2bfloat16(w);
    const float fh = __bfloat162float(bh);
    const float r1 = w - fh;                  // exact
    __hip_bfloat16 bm = __float2bfloat16(r1);
    const float fm = __bfloat162float(bm);
    __hip_bfloat16 bl = __float2bfloat16(r1 - fm);  // exact residual (8 bits left)
    h = *(unsigned short*)&bh; m = *(unsigned short*)&bm; l = *(unsigned short*)&bl;
}

__global__ void split_w(const float* __restrict__ W,
                        unsigned short* __restrict__ ph,
                        unsigned short* __restrict__ pm,
                        unsigned short* __restrict__ pl, int n)
{
    const int i = blockIdx.x * 256 + threadIdx.x;
    if (i >= n) return;
    split_bf16x3(W[i], ph[i], pm[i], pl[i]);
}

// ============ spike MFMA GEMM — NEW 256x128, BK=32, ms=4/ns=4 =============
// Retile: wave = 64 rows x 64 cols. Each unpacked A-fragment now feeds 12
// MFMAs (was 6) -> unpack VALU per MFMA halves; B-reads unchanged; acc=64
// VGPR; B-LDS stays 48 KB dbuf -> occupancy preserved. Reg-A dbuf + fast
// unpack + fused BN stats kept from R14. Accumulation reorder within each
// 64-K group (same partial products) — same noise class as prior passes.
__global__ __launch_bounds__(512) void mfma_spk_gemm(
    const unsigned long long* __restrict__ S,  // [K/64][Mstr] u64
    int Mstr,                                  // row stride (= MM)
    const unsigned short* __restrict__ Wh,     // [N,K] bf16 planes
    const unsigned short* __restrict__ Wm,
    const unsigned short* __restrict__ Wl,
    float* __restrict__ CA,                    // rows [0, MHALF)
    float* __restrict__ CB,                    // rows [MHALF, M)
    float* __restrict__ part,                  // [chunks][2][N]
    int M, int N, int K)
{
    __shared__ __align__(16) unsigned short Blds[2][3][128][32];  // 48 KB
    __shared__ float SredS[3][2][2][64];                          // 3 KB
    const int tid = threadIdx.x;
    const int wv = tid >> 6;                 // 0..7
    const int lane = tid & 63;
    const int wm = wv >> 1, wn = wv & 1;     // wm 0..3 (64 rows), wn 0..1 (64 cols)
    const int r16 = lane & 15, quad = lane >> 4;
    const int bm = blockIdx.x * 256;
    const int bn = blockIdx.y * 128;
    const unsigned int q8 = quad * 8;

    f4v acc[4][4] = {};

    // B staging: 24 issues per tile (3 planes x 8 row-octets), 3 per wave
    const int rl = lane >> 2, chl = lane & 3;
    const unsigned short* sW[3];
    size_t sOff[3];
    int sP[3], sR8[3];
#pragma unroll
    for (int i = 0; i < 3; ++i) {
        const int e = wv * 3 + i;            // 0..23
        const int p = e >> 3, r8 = e & 7;
        const int srow = r8 * 16 + rl;       // 0..127
        const int kc = (chl - (srow >> 1)) & 3;
        sW[i] = (p == 0) ? Wh : (p == 1) ? Wm : Wl;
        sOff[i] = (size_t)(bn + srow) * K + kc * 8;  // ushort units
        sP[i] = p; sR8[i] = r8;
    }

    // per-thread A word u32 addresses (x2 row index within S viewed as u32)
    const unsigned int* __restrict__ S32 = (const unsigned int*)S;
    const size_t MROW2 = 2 * (size_t)Mstr;
    unsigned int abase2[4];
#pragma unroll
    for (int ms = 0; ms < 4; ++ms)
        abase2[ms] = 2u * (unsigned)(bm + wm * 64 + ms * 16 + r16);

    int bR[4], bC[4];
#pragma unroll
    for (int ns = 0; ns < 4; ++ns) {
        bR[ns] = wn * 64 + ns * 16 + r16;                // 0..127
        bC[ns] = ((quad + (bR[ns] >> 1)) & 3) * 8;
    }

    auto stageB = [&](int buf, int i, int k0) {
        __builtin_amdgcn_global_load_lds(
            (const __attribute__((address_space(1))) void*)(sW[i] + sOff[i] + k0),
            (__attribute__((address_space(3))) void*)&Blds[buf][sP[i]][sR8[i] * 16][0],
            16, 0, 0);
    };

    const int NT = K >> 5;    // 64 (even)

    // prologue: A u32 words for t=0 (tk=0, half=0); stage B tile 0 -> buf 0
    unsigned int a32A[4], a32B[4];
#pragma unroll
    for (int ms = 0; ms < 4; ++ms) a32A[ms] = S32[abase2[ms]];
#pragma unroll
    for (int i = 0; i < 3; ++i) stageB(0, i, 0);
    __syncthreads();

// one K-step (BK=32): prefetch next (B stages + A regs), unpack CURA,
// 3 phases {4 ds_read_b128 ; setprio ; 16 MFMA}, end barrier.
#define SPK_STEP(CURA, NXTA, CURL, NXTL, T)                                  \
    do {                                                                     \
        if ((T) + 1 < NT) {                                                  \
            _Pragma("unroll")                                                \
            for (int i = 0; i < 3; ++i) stageB((NXTL), i, ((T) + 1) << 5);   \
            _Pragma("unroll")                                                \
            for (int ms = 0; ms < 4; ++ms)                                   \
                NXTA[ms] = S32[(size_t)(((T) + 1) >> 1) * MROW2              \
                               + abase2[ms] + (((T) + 1) & 1)];              \
        }                                                                    \
        s8v afr[4];                                                          \
        _Pragma("unroll")                                                    \
        for (int ms = 0; ms < 4; ++ms) {                                     \
            const unsigned int w = CURA[ms];                                 \
            const unsigned int bl = (w >> q8) & 0xFu;                        \
            const unsigned int bh = (w >> (q8 + 4)) & 0xFu;                  \
            const unsigned int lo = (bl * 0x00204081u) & 0x01010101u;        \
            const unsigned int hi = (bh * 0x00204081u) & 0x01010101u;        \
            ABu tu;                                                          \
            tu.u[0] = __builtin_amdgcn_perm(0u, lo, 0x04010400u) * 0x3F80u;  \
            tu.u[1] = __builtin_amdgcn_perm(0u, lo, 0x04030402u) * 0x3F80u;  \
            tu.u[2] = __builtin_amdgcn_perm(0u, hi, 0x04010400u) * 0x3F80u;  \
            tu.u[3] = __builtin_amdgcn_perm(0u, hi, 0x04030402u) * 0x3F80u;  \
            afr[ms] = tu.v;                                                  \
        }                                                                    \
        _Pragma("unroll")                                                    \
        for (int p = 0; p < 3; ++p) {                                        \
            s8v bf[4];                                                       \
            _Pragma("unroll")                                                \
            for (int ns = 0; ns < 4; ++ns)                                   \
                bf[ns] = *(const s8v*)&Blds[CURL][p][bR[ns]][bC[ns]];        \
            __builtin_amdgcn_s_setprio(1);                                   \
            _Pragma("unroll")                                                \
            for (int ms = 0; ms < 4; ++ms)                                   \
                _Pragma("unroll")                                            \
                for (int ns = 0; ns < 4; ++ns)                               \
                    acc[ms][ns] = __builtin_amdgcn_mfma_f32_16x16x32_bf16(   \
                        afr[ms], bf[ns], acc[ms][ns], 0, 0, 0);              \
            __builtin_amdgcn_s_setprio(0);                                   \
        }                                                                    \
        if ((T) + 1 < NT) __syncthreads();                                   \
    } while (0)

    for (int t = 0; t < NT; t += 2) {
        SPK_STEP(a32A, a32B, 0, 1, t);
        SPK_STEP(a32B, a32A, 1, 0, t + 1);
    }
#undef SPK_STEP

    // ---- fused BN partial stats: per-col sums of this block's 256 rows ----
    float s1v[4], s2v[4];
#pragma unroll
    for (int ns = 0; ns < 4; ++ns) {
        float s = 0.f, s2 = 0.f;
#pragma unroll
        for (int ms = 0; ms < 4; ++ms)
#pragma unroll
            for (int r = 0; r < 4; ++r) {
                const float v = acc[ms][ns][r];
                s += v;
                s2 = fmaf(v, v, s2);
            }
        s += __shfl_down(s, 32);  s += __shfl_down(s, 16);
        s2 += __shfl_down(s2, 32); s2 += __shfl_down(s2, 16);
        s1v[ns] = s; s2v[ns] = s2;
    }
    __syncthreads();
    if (wm > 0 && lane < 16) {
#pragma unroll
        for (int ns = 0; ns < 4; ++ns) {
            SredS[wm - 1][wn][0][ns * 16 + lane] = s1v[ns];
            SredS[wm - 1][wn][1][ns * 16 + lane] = s2v[ns];
        }
    }
    __syncthreads();
    if (wm == 0 && lane < 16) {
#pragma unroll
        for (int ns = 0; ns < 4; ++ns) {
            const int col = bn + wn * 64 + ns * 16 + lane;
            const int li = ns * 16 + lane;
            const float s  = s1v[ns] + SredS[0][wn][0][li] + SredS[1][wn][0][li] + SredS[2][wn][0][li];
            const float s2 = s2v[ns] + SredS[0][wn][1][li] + SredS[1][wn][1][li] + SredS[2][wn][1][li];
            part[((size_t)blockIdx.x * 2 + 0) * N + col] = s;
            part[((size_t)blockIdx.x * 2 + 1) * N + col] = s2;
        }
    }

    // ---- C store (half select by bm; 256-row block lies in one half) ----
    float* __restrict__ CO = (bm < MHALF) ? CA : CB;
    const int rsub = (bm < MHALF) ? 0 : MHALF;
#pragma unroll
    for (int ms = 0; ms < 4; ++ms)
#pragma unroll
        for (int ns = 0; ns < 4; ++ns) {
            const int row = bm - rsub + wm * 64 + ms * 16 + quad * 4;
            const int col = bn + wn * 64 + ns * 16 + r16;
#pragma unroll
            for (int r = 0; r < 4; ++r)
                CO[(size_t)(row + r) * N + col] = acc[ms][ns][r];
        }
}

// ============ f32-via-bf16x3 MFMA GEMM — R14-proven (control) =============
struct Sp3 { unsigned int o0, o1, o2; };

__device__ inline Sp3 split_pair(float x, float y)
{
    const unsigned int xb = __float_as_uint(x), yb = __float_as_uint(y);
    const unsigned int x0 = xb & 0xFFFF0000u,  y0 = yb & 0xFFFF0000u;
    const float xr1 = x - __uint_as_float(x0), yr1 = y - __uint_as_float(y0);
    const unsigned int x1b = __float_as_uint(xr1), y1b = __float_as_uint(yr1);
    const unsigned int x1 = x1b & 0xFFFF0000u, y1 = y1b & 0xFFFF0000u;
    const float xr2 = xr1 - __uint_as_float(x1), yr2 = yr1 - __uint_as_float(y1);
    Sp3 r;
    // pack bf16 pair (x in low16, y in high16) = bytes [x.b2,x.b3,y.b2,y.b3]
    r.o0 = __builtin_amdgcn_perm(yb, xb, 0x07060302u);
    r.o1 = __builtin_amdgcn_perm(y1b, x1b, 0x07060302u);
    r.o2 = __builtin_amdgcn_perm(__float_as_uint(yr2), __float_as_uint(xr2), 0x07060302u);
    return r;
}

__global__ __launch_bounds__(256) void mfma_f32x3_gemm(
    const float* __restrict__ A,            // [M,K] f32 (full M)
    const unsigned short* __restrict__ Wh,  // [N,K] bf16 planes (exact sum)
    const unsigned short* __restrict__ Wm,
    const unsigned short* __restrict__ Wl,
    float* __restrict__ CA,                 // rows [0, MHALF)
    float* __restrict__ CB,                 // rows [MHALF, M)
    float* __restrict__ part,               // [chunks][2][N]
    int M, int N, int K)
{
    __shared__ __align__(16) unsigned short Blds[2][3][128][32];  // 48 KB dbuf
    __shared__ float SredF[2][2][64];                             // 1 KB
    const int tid = threadIdx.x;
    const int wv = tid >> 6;
    const int lane = tid & 63;
    const int wm = wv >> 1, wn = wv & 1;
    const int r16 = lane & 15, quad = lane >> 4;

    // XCD-chunked panel swizzle (bijective: 8 XCDs x 32 panels x 16 N-tiles)
    const int lin = blockIdx.y * 16 + blockIdx.x;   // dispatch-order index
    const int ppx = gridDim.y >> 3;                 // M-panels per XCD (32)
    const int xcd = lin & 7, li = lin >> 3;
    const int pm = xcd * ppx + (li >> 4);           // 0..255 global M-tile
    const int pn = li & 15;
    const int bm = pm * 128;
    const int bn = pn * 128;

    f4v acc[4][4] = {};

    const int rl = lane >> 2, chl = lane & 3;
    size_t soff[2];
    int ldsrow[2];
#pragma unroll
    for (int i = 0; i < 2; ++i) {
        const int r = i * 64 + wv * 16 + rl;           // 0..127
        const int kc = (chl - (r >> 1)) & 3;
        soff[i] = (size_t)(bn + r) * K + kc * 8;       // ushort units
        ldsrow[i] = i * 64 + wv * 16;
    }

    size_t aoff[4];
#pragma unroll
    for (int ms = 0; ms < 4; ++ms)
        aoff[ms] = (size_t)(bm + wm * 64 + ms * 16 + r16) * K + quad * 8;  // f32

    int bR[4], bC[4];
#pragma unroll
    for (int ns = 0; ns < 4; ++ns) {
        bR[ns] = wn * 64 + ns * 16 + r16;
        bC[ns] = ((quad + (bR[ns] >> 1)) & 3) * 8;
    }

    auto stage = [&](int buf, int p, int i, int k0) {
        const unsigned short* Wp = (p == 0) ? Wh : (p == 1) ? Wm : Wl;
        __builtin_amdgcn_global_load_lds(
            (const __attribute__((address_space(1))) void*)(Wp + soff[i] + k0),
            (__attribute__((address_space(3))) void*)&Blds[buf][p][ldsrow[i]][0], 16, 0, 0);
    };

    float4 av[4][2];
#pragma unroll
    for (int ms = 0; ms < 4; ++ms) {
        av[ms][0] = *(const float4*)(A + aoff[ms]);
        av[ms][1] = *(const float4*)(A + aoff[ms] + 4);
    }
#pragma unroll
    for (int p = 0; p < 3; ++p)
#pragma unroll
        for (int i = 0; i < 2; ++i) stage(0, p, i, 0);
    __syncthreads();

    const int NT = K >> 5;   // BK=32
    for (int t = 0; t < NT; ++t) {
        const int cur = t & 1, nxt = cur ^ 1;
        const int k0 = t << 5;

        if (t + 1 < NT) {
#pragma unroll
            for (int p = 0; p < 3; ++p)
#pragma unroll
                for (int i = 0; i < 2; ++i) stage(nxt, p, i, k0 + 32);
        }

        s8v afr[3][4];
#pragma unroll
        for (int ms = 0; ms < 4; ++ms) {
            ABu t0, t1, t2;
            const float4 v0 = av[ms][0];
            const float4 v1 = av[ms][1];
            const Sp3 s0 = split_pair(v0.x, v0.y);
            const Sp3 s1 = split_pair(v0.z, v0.w);
            const Sp3 s2 = split_pair(v1.x, v1.y);
            const Sp3 s3 = split_pair(v1.z, v1.w);
            t0.u[0] = s0.o0; t1.u[0] = s0.o1; t2.u[0] = s0.o2;
            t0.u[1] = s1.o0; t1.u[1] = s1.o1; t2.u[1] = s1.o2;
            t0.u[2] = s2.o0; t1.u[2] = s2.o1; t2.u[2] = s2.o2;
            t0.u[3] = s3.o0; t1.u[3] = s3.o1; t2.u[3] = s3.o2;
            afr[0][ms] = t0.v;
            afr[1][ms] = t1.v;
            afr[2][ms] = t2.v;
        }
        if (t + 1 < NT) {
#pragma unroll
            for (int ms = 0; ms < 4; ++ms) {
                av[ms][0] = *(const float4*)(A + aoff[ms] + k0 + 32);
                av[ms][1] = *(const float4*)(A + aoff[ms] + k0 + 32 + 4);
            }
        }

#pragma unroll
        for (int pw = 0; pw < 3; ++pw) {
            s8v bf[4];
#pragma unroll
            for (int ns = 0; ns < 4; ++ns)
                bf[ns] = *(const s8v*)&Blds[cur][pw][bR[ns]][bC[ns]];
            __builtin_amdgcn_s_setprio(1);
#pragma unroll
            for (int pa = 0; pa + pw < 3; ++pa)
#pragma unroll
                for (int ms = 0; ms < 4; ++ms)
#pragma unroll
                    for (int ns = 0; ns < 4; ++ns)
                        acc[ms][ns] = __builtin_amdgcn_mfma_f32_16x16x32_bf16(
                            afr[pa][ms], bf[ns], acc[ms][ns], 0, 0, 0);
            __builtin_amdgcn_s_setprio(0);
        }

        if (t + 1 < NT) __syncthreads();
    }

    // ---- fused BN partial stats: per-col sums of this block's 128 rows ----
    float s1v[4], s2v[4];
#pragma unroll
    for (int ns = 0; ns < 4; ++ns) {
        float s = 0.f, s2 = 0.f;
#pragma unroll
        for (int ms = 0; ms < 4; ++ms)
#pragma unroll
            for (int r = 0; r < 4; ++r) {
                const float v = acc[ms][ns][r];
                s += v;
                s2 = fmaf(v, v, s2);
            }
        s += __shfl_down(s, 32);  s += __shfl_down(s, 16);
        s2 += __shfl_down(s2, 32); s2 += __shfl_down(s2, 16);
        s1v[ns] = s; s2v[ns] = s2;
    }
    __syncthreads();
    if (wm == 1 && lane < 16) {
#pragma unroll
        for (int ns = 0; ns < 4; ++ns) {
            SredF[wn][0][ns * 16 + lane] = s1v[ns];
            SredF[wn][1][ns * 16 + lane] = s2v[ns];
        }
    }
    __syncthreads();
    if (wm == 0 && lane < 16) {
#pragma unroll
        for (int ns = 0; ns < 4; ++ns) {
            const int col = bn + wn * 64 + ns * 16 + lane;
            const int li = ns * 16 + lane;
            part[((size_t)pm * 2 + 0) * N + col] = s1v[ns] + SredF[wn][0][li];
            part[((size_t)pm * 2 + 1) * N + col] = s2v[ns] + SredF[wn][1][li];
        }
    }

    // ---- C store (half select by bm) ----
    float* __restrict__ CO = (bm < MHALF) ? CA : CB;
    const int rsub = (bm < MHALF) ? 0 : MHALF;
#pragma unroll
    for (int ms = 0; ms < 4; ++ms)
#pragma unroll
        for (int ns = 0; ns < 4; ++ns) {
            const int row = bm - rsub + wm * 64 + ms * 16 + quad * 4;
            const int col = bn + wn * 64 + ns * 16 + r16;
#pragma unroll
            for (int r = 0; r < 4; ++r)
                CO[(size_t)(row + r) * N + col] = acc[ms][ns][r];
        }
}

// ============ BN stats finalize (partials come from GEMM epilogues) =======
__global__ void bn_stats_final(const float* __restrict__ partial,
                               float* __restrict__ stats,
                               int N, int nchunks)
{
    const int n = blockIdx.x * 256 + threadIdx.x;
    double s = 0.0, s2 = 0.0;
    for (int c = 0; c < nchunks; ++c) {
        s  += (double)partial[((size_t)c * 2 + 0) * N + n];
        s2 += (double)partial[((size_t)c * 2 + 1) * N + n];
    }
    const double inv_m = 1.0 / (double)MM;
    const double mu = s * inv_m;
    const double var = s2 * inv_m - mu * mu;
    stats[n]     = (float)mu;
    stats[N + n] = (float)(1.0 / sqrt(var + 1e-5));
}

// ============ fused BN + LIF scan — pack writes TRANSPOSED spikes =========
#define LIF_STEP_PACK(hv)                                            \
    do {                                                             \
        const float hn = ((hv) - mu) * rstd * g + bi;                \
        u = beta * (u - s) + omb * hn;                               \
        const bool sp = (u - 1.0f) >= 0.f;                           \
        s = sp ? 1.f : 0.f;                                          \
        const unsigned long long mball = __ballot(sp);               \
        if (lead) bits[widx] = mball;                                \
        ++widx;                                                      \
    } while (0)

#define LIF_LOAD8(buf, tbase)                                        \
    _Pragma("unroll")                                                \
    for (int j = 0; j < 8; ++j) {                                    \
        const int tl = (tbase) + j;                                  \
        buf[j] = h[base + (size_t)(tl < TT ? tl : TT - 1) * N];      \
    }

__global__ __launch_bounds__(64) void bn_lif_scan_pack2(
    const float* __restrict__ hA,      // [MHALF, N]  (b < 16)
    const float* __restrict__ hB,      // [MHALF, N]  (b >= 16)
    unsigned long long* __restrict__ bits,  // [N/64][MM] transposed
    const float* __restrict__ stats,
    const float* __restrict__ gamma,
    const float* __restrict__ bias,
    const float* __restrict__ beta_p,
    const float* __restrict__ U0,      // [BB, N]
    int N)
{
    const int n = blockIdx.x * 64 + threadIdx.x;
    const int b = blockIdx.y;                       // global batch 0..31
    const float* __restrict__ h = (b < BB / 2) ? hA : hB;
    const int bl = b & (BB / 2 - 1);
    const float mu = stats[n];
    const float rstd = stats[N + n];
    const float g = gamma[n];
    const float bi = bias[n];
    const float beta = 1.f / (1.f + expf(-beta_p[n]));
    const float omb = 1.f - beta;
    float u = U0[(size_t)b * N + n];
    float s = 0.f;
    const size_t base = ((size_t)bl * TT) * N + n;
    size_t widx = (size_t)(n >> 6) * (size_t)MM + (size_t)b * TT;
    const bool lead = (threadIdx.x & 63) == 0;

    float b0[8], b1[8], b2[8], b3[8];
    LIF_LOAD8(b0, 0);
    LIF_LOAD8(b1, 8);
    LIF_LOAD8(b2, 16);
    for (int t0 = 0; t0 < TT; t0 += 32) {
        LIF_LOAD8(b3, t0 + 24);
#pragma unroll
        for (int j = 0; j < 8; ++j) { const float hv = b0[j]; LIF_STEP_PACK(hv); }
        LIF_LOAD8(b0, t0 + 32);
#pragma unroll
        for (int j = 0; j < 8; ++j) { const float hv = b1[j]; LIF_STEP_PACK(hv); }
        LIF_LOAD8(b1, t0 + 40);
#pragma unroll
        for (int j = 0; j < 8; ++j) { const float hv = b2[j]; LIF_STEP_PACK(hv); }
        LIF_LOAD8(b2, t0 + 48);
#pragma unroll
        for (int j = 0; j < 8; ++j) { const float hv = b3[j]; LIF_STEP_PACK(hv); }
    }
}

#define LIF_STEP_F32(hv)                                             \
    do {                                                             \
        const float hn = ((hv) - mu) * rstd * g + bi;                \
        u = beta * (u - s) + omb * hn;                               \
        s = ((u - 1.0f) >= 0.f) ? 1.f : 0.f;                         \
        out[oidx] = s;                                               \
        oidx += N;                                                   \
    } while (0)

__global__ __launch_bounds__(64) void bn_lif_scan_f32_2(
    const float* __restrict__ h,       // [MM, N] (full)
    float* __restrict__ out,
    const float* __restrict__ stats,
    const float* __restrict__ gamma,
    const float* __restrict__ bias,
    const float* __restrict__ beta_p,
    const float* __restrict__ U0,
    int N)
{
    const int n = blockIdx.x * 64 + threadIdx.x;
    const int b = blockIdx.y;
    const float mu = stats[n];
    const float rstd = stats[N + n];
    const float g = gamma[n];
    const float bi = bias[n];
    const float beta = 1.f / (1.f + expf(-beta_p[n]));
    const float omb = 1.f - beta;
    float u = U0[(size_t)b * N + n];
    float s = 0.f;
    const size_t base = ((size_t)b * TT) * N + n;
    size_t oidx = base;

    float b0[8], b1[8], b2[8], b3[8];
    LIF_LOAD8(b0, 0);
    LIF_LOAD8(b1, 8);
    LIF_LOAD8(b2, 16);
    for (int t0 = 0; t0 < TT; t0 += 32) {
        LIF_LOAD8(b3, t0 + 24);
#pragma unroll
        for (int j = 0; j < 8; ++j) { const float hv = b0[j]; LIF_STEP_F32(hv); }
        LIF_LOAD8(b0, t0 + 32);
#pragma unroll
        for (int j = 0; j < 8; ++j) { const float hv = b1[j]; LIF_STEP_F32(hv); }
        LIF_LOAD8(b1, t0 + 40);
#pragma unroll
        for (int j = 0; j < 8; ++j) { const float hv = b2[j]; LIF_STEP_F32(hv); }
        LIF_LOAD8(b2, t0 + 48);
#pragma unroll
        for (int j = 0; j < 8; ++j) { const float hv = b3[j]; LIF_STEP_F32(hv); }
    }
}

// ============ launcher ====================================================
extern "C" void kernel_launch(void* const* d_in, const int* in_sizes, int n_in,
                              void* d_out, int out_size, void* d_ws, size_t ws_size,
                              hipStream_t stream)
{
    const float* x   = (const float*)d_in[0];
    const float* W1  = (const float*)d_in[1];
    const float* bp1 = (const float*)d_in[2];
    const float* g1  = (const float*)d_in[3];
    const float* bi1 = (const float*)d_in[4];
    const float* U01 = (const float*)d_in[5];
    const float* W2  = (const float*)d_in[6];
    const float* bp2 = (const float*)d_in[7];
    const float* g2  = (const float*)d_in[8];
    const float* bi2 = (const float*)d_in[9];
    const float* U02 = (const float*)d_in[10];
    const float* W3  = (const float*)d_in[11];
    const float* bp3 = (const float*)d_in[12];
    const float* g3  = (const float*)d_in[13];
    const float* bi3 = (const float*)d_in[14];
    const float* U03 = (const float*)d_in[15];
    float* out = (float*)d_out;

    // ws layout (unchanged, ~185 MB): hA | spk | part | stat | W2/W3 planes
    unsigned char* ws = (unsigned char*)d_ws;
    const size_t HA_BYTES  = (size_t)MHALF * HH * sizeof(float);  // 134217728
    const size_t SPK_BYTES = (size_t)MM * (HH / 8);               // 8388608
    float*              hA   = (float*)ws;
    float*              hB   = (float*)d_out;  // scratch until final scan
    unsigned long long* spk  = (unsigned long long*)(ws + HA_BYTES);
    float*              part = (float*)(ws + HA_BYTES + SPK_BYTES);
    float*              stat = (float*)(ws + HA_BYTES + SPK_BYTES + 4194304);
    unsigned short*     W2h  = (unsigned short*)(ws + HA_BYTES + SPK_BYTES + 4194304 + 16384);
    unsigned short*     W2m  = W2h + (size_t)HH * HH;
    unsigned short*     W2l  = W2m + (size_t)HH * HH;
    unsigned short*     W3h  = W2l + (size_t)HH * HH;
    unsigned short*     W3m  = W3h + (size_t)JJ * HH;
    unsigned short*     W3l  = W3m + (size_t)JJ * HH;

    const dim3 blk(256);
    const dim3 blk64(64);
    const dim3 blk512(512);

    // ---- Layer 1: x[M,J](f32) * W1[H,J]^T via 6-term bf16x3 MFMA ----
    split_w<<<dim3((HH * JJ) / 256), blk, 0, stream>>>(W1, W2h, W2m, W2l, HH * JJ);
    mfma_f32x3_gemm<<<dim3(HH / 128, MM / 128), blk, 0, stream>>>(
        x, W2h, W2m, W2l, hA, hB, part, MM, HH, JJ);
    // now W1 planes are dead — split W2/W3 into their home slots
    split_w<<<dim3((HH * HH) / 256), blk, 0, stream>>>(W2, W2h, W2m, W2l, HH * HH);
    split_w<<<dim3((JJ * HH) / 256), blk, 0, stream>>>(W3, W3h, W3m, W3l, JJ * HH);

    bn_stats_final<<<dim3(HH / 256), blk, 0, stream>>>(part, stat, HH, MM / 128);
    bn_lif_scan_pack2<<<dim3(HH / 64, BB), blk64, 0, stream>>>(
        hA, hB, spk, stat, g1, bi1, bp1, U01, HH);

    // ---- Layer 2: spk[H/64][MM] * W2[H,H]^T (256x128 retile) ----
    mfma_spk_gemm<<<dim3(MM / 256, HH / 128), blk512, 0, stream>>>(
        spk, MM, W2h, W2m, W2l, hA, hB, part, MM, HH, HH);
    bn_stats_final<<<dim3(HH / 256), blk, 0, stream>>>(part, stat, HH, MM / 256);
    bn_lif_scan_pack2<<<dim3(HH / 64, BB), blk64, 0, stream>>>(
        hA, hB, spk, stat, g2, bi2, bp2, U02, HH);

    // ---- Layer 3: spk[H/64][MM] * W3[J,H]^T -> hA [M,1024] ----
    mfma_spk_gemm<<<dim3(MM / 256, JJ / 128), blk512, 0, stream>>>(
        spk, MM, W3h, W3m, W3l, hA, hA + (size_t)MHALF * JJ, part, MM, JJ, HH);
    bn_stats_final<<<dim3(JJ / 256), blk, 0, stream>>>(part, stat, JJ, MM / 256);
    bn_lif_scan_f32_2<<<dim3(JJ / 64, BB), blk64, 0, stream>>>(
        hA, out, stat, g3, bi3, bp3, U03, JJ);
}

// Round 16
// 2248.977 us; speedup vs baseline: 1.0628x; 1.0628x over previous
//
#include <hip/hip_runtime.h>
#include <hip/hip_bf16.h>
#include <cmath>

// Problem constants: B=32, T=1024, J=1024, H=2048
#define BB 32
#define TT 1024
#define JJ 1024
#define HH 2048
#define MM (BB * TT)      // 32768 rows
#define MHALF (MM / 2)    // 16384

typedef short s8v __attribute__((ext_vector_type(8)));   // 8 bf16 raw
typedef float f4v __attribute__((ext_vector_type(4)));
typedef unsigned int u4v __attribute__((ext_vector_type(4)));
union ABu { u4v u; s8v v; };

// ============ exact f32 -> bf16 hi/mid/lo (w == h+m+l exactly) ============
__device__ inline void split_bf16x3(float w, unsigned short& h,
                                    unsigned short& m, unsigned short& l) {
    __hip_bfloat16 bh = __float2bfloat16(w);
    const float fh = __bfloat162float(bh);
    const float r1 = w - fh;                  // exact
    __hip_bfloat16 bm = __float2bfloat16(r1);
    const float fm = __bfloat162float(bm);
    __hip_bfloat16 bl = __float2bfloat16(r1 - fm);  // exact residual (8 bits left)
    h = *(unsigned short*)&bh; m = *(unsigned short*)&bm; l = *(unsigned short*)&bl;
}

__global__ void split_w(const float* __restrict__ W,
                        unsigned short* __restrict__ ph,
                        unsigned short* __restrict__ pm,
                        unsigned short* __restrict__ pl, int n)
{
    const int i = blockIdx.x * 256 + threadIdx.x;
    if (i >= n) return;
    split_bf16x3(W[i], ph[i], pm[i], pl[i]);
}

// ============ spike MFMA GEMM — 512x64, reg-A dbuf, FUSED BN-STATS ========
// R14-proven configuration (R15's 256x128 retile regressed: it doubled
// B-LDS reads per FLOP — ms=8/ns=2 gives 8 MFMA per ds_read_b128, the
// VGPR-feasible max; this structure is LDS-BW-bound at ~46% MfmaUtil).
__global__ __launch_bounds__(512) void mfma_spk_gemm(
    const unsigned long long* __restrict__ S,  // [K/64][Mstr] u64
    int Mstr,                                  // row stride (= MM)
    const unsigned short* __restrict__ Wh,     // [N,K] bf16 planes
    const unsigned short* __restrict__ Wm,
    const unsigned short* __restrict__ Wl,
    float* __restrict__ CA,                    // rows [0, MHALF)
    float* __restrict__ CB,                    // rows [MHALF, M)
    float* __restrict__ part,                  // [chunks][2][N]
    int M, int N, int K)
{
    __shared__ __align__(16) unsigned short Blds[2][3][2][64][32];  // 48 KB
    __shared__ float SredS[3][2][2][32];                            // 1.5 KB
    const int tid = threadIdx.x;
    const int wv = tid >> 6;                 // 0..7
    const int lane = tid & 63;
    const int wm = wv >> 1, wn = wv & 1;     // wm 0..3 (128 rows), wn 0..1 (32 cols)
    const int r16 = lane & 15, quad = lane >> 4;
    const int bm = blockIdx.x * 512;
    const int bn = blockIdx.y * 64;
    const unsigned int q8 = quad * 8;

    f4v acc[8][2] = {};

    // B staging (proven swizzle): 24 issues per tile, 3 per wave
    const int rl = lane >> 2, chl = lane & 3;
    const unsigned short* sW[3];
    size_t sOff[3];
    int sP[3], sKh[3], sQ[3];
#pragma unroll
    for (int i = 0; i < 3; ++i) {
        const int e = wv * 3 + i;
        const int p = e >> 3, kh = (e >> 2) & 1, q = e & 3;
        const int srow = q * 16 + rl;                    // 0..63
        const int kc = (chl - (srow >> 1)) & 3;
        sW[i] = (p == 0) ? Wh : (p == 1) ? Wm : Wl;
        sOff[i] = (size_t)(bn + srow) * K + kh * 32 + kc * 8;  // ushort units
        sP[i] = p; sKh[i] = kh; sQ[i] = q;
    }

    size_t abase[8];
#pragma unroll
    for (int ms = 0; ms < 8; ++ms)
        abase[ms] = (size_t)(bm + wm * 128 + ms * 16 + r16);

    int bR[2], bC[2];
#pragma unroll
    for (int ns = 0; ns < 2; ++ns) {
        bR[ns] = wn * 32 + ns * 16 + r16;                // 0..63
        bC[ns] = ((quad + (bR[ns] >> 1)) & 3) * 8;
    }

    auto stageB = [&](int buf, int i, int k0) {
        __builtin_amdgcn_global_load_lds(
            (const __attribute__((address_space(1))) void*)(sW[i] + sOff[i] + k0),
            (__attribute__((address_space(3))) void*)&Blds[buf][sP[i]][sKh[i]][sQ[i] * 16][0],
            16, 0, 0);
    };

    const int NT = K >> 6;    // 32 (even)

    unsigned long long a64A[8], a64B[8];
#pragma unroll
    for (int ms = 0; ms < 8; ++ms) a64A[ms] = S[abase[ms]];
#pragma unroll
    for (int i = 0; i < 3; ++i) stageB(0, i, 0);
    __syncthreads();

#define SPK_STEP(CURA, NXTA, CURL, NXTL, T)                                  \
    do {                                                                     \
        if ((T) + 1 < NT) {                                                  \
            _Pragma("unroll")                                                \
            for (int i = 0; i < 3; ++i) stageB((NXTL), i, ((T) + 1) << 6);   \
            _Pragma("unroll")                                                \
            for (int ms = 0; ms < 8; ++ms)                                   \
                NXTA[ms] = S[(size_t)((T) + 1) * Mstr + abase[ms]];          \
        }                                                                    \
        s8v afr[2][8];                                                       \
        _Pragma("unroll")                                                    \
        for (int ms = 0; ms < 8; ++ms) {                                     \
            const unsigned int w0 = (unsigned int)CURA[ms];                  \
            const unsigned int w1 = (unsigned int)(CURA[ms] >> 32);          \
            _Pragma("unroll")                                                \
            for (int kh = 0; kh < 2; ++kh) {                                 \
                const unsigned int w = kh ? w1 : w0;                         \
                const unsigned int bl = (w >> q8) & 0xFu;                    \
                const unsigned int bh = (w >> (q8 + 4)) & 0xFu;              \
                const unsigned int lo = (bl * 0x00204081u) & 0x01010101u;    \
                const unsigned int hi = (bh * 0x00204081u) & 0x01010101u;    \
                ABu tu;                                                      \
                tu.u[0] = __builtin_amdgcn_perm(0u, lo, 0x04010400u) * 0x3F80u; \
                tu.u[1] = __builtin_amdgcn_perm(0u, lo, 0x04030402u) * 0x3F80u; \
                tu.u[2] = __builtin_amdgcn_perm(0u, hi, 0x04010400u) * 0x3F80u; \
                tu.u[3] = __builtin_amdgcn_perm(0u, hi, 0x04030402u) * 0x3F80u; \
                afr[kh][ms] = tu.v;                                          \
            }                                                                \
        }                                                                    \
        _Pragma("unroll")                                                    \
        for (int p = 0; p < 3; ++p)                                          \
            _Pragma("unroll")                                                \
            for (int kh = 0; kh < 2; ++kh) {                                 \
                s8v bf[2];                                                   \
                _Pragma("unroll")                                            \
                for (int ns = 0; ns < 2; ++ns)                               \
                    bf[ns] = *(const s8v*)&Blds[CURL][p][kh][bR[ns]][bC[ns]];\
                __builtin_amdgcn_s_setprio(1);                               \
                _Pragma("unroll")                                            \
                for (int ms = 0; ms < 8; ++ms)                               \
                    _Pragma("unroll")                                        \
                    for (int ns = 0; ns < 2; ++ns)                           \
                        acc[ms][ns] = __builtin_amdgcn_mfma_f32_16x16x32_bf16( \
                            afr[kh][ms], bf[ns], acc[ms][ns], 0, 0, 0);      \
                __builtin_amdgcn_s_setprio(0);                               \
            }                                                                \
        if ((T) + 1 < NT) __syncthreads();                                   \
    } while (0)

    for (int t = 0; t < NT; t += 2) {
        SPK_STEP(a64A, a64B, 0, 1, t);
        SPK_STEP(a64B, a64A, 1, 0, t + 1);
    }
#undef SPK_STEP

    // ---- fused BN partial stats: per-col sums of this block's 512 rows ----
    float s1v[2], s2v[2];
#pragma unroll
    for (int ns = 0; ns < 2; ++ns) {
        float s = 0.f, s2 = 0.f;
#pragma unroll
        for (int ms = 0; ms < 8; ++ms)
#pragma unroll
            for (int r = 0; r < 4; ++r) {
                const float v = acc[ms][ns][r];
                s += v;
                s2 = fmaf(v, v, s2);
            }
        s += __shfl_down(s, 32);  s += __shfl_down(s, 16);
        s2 += __shfl_down(s2, 32); s2 += __shfl_down(s2, 16);
        s1v[ns] = s; s2v[ns] = s2;
    }
    __syncthreads();
    if (wm > 0 && lane < 16) {
#pragma unroll
        for (int ns = 0; ns < 2; ++ns) {
            SredS[wm - 1][wn][0][ns * 16 + lane] = s1v[ns];
            SredS[wm - 1][wn][1][ns * 16 + lane] = s2v[ns];
        }
    }
    __syncthreads();
    if (wm == 0 && lane < 16) {
#pragma unroll
        for (int ns = 0; ns < 2; ++ns) {
            const int col = bn + wn * 32 + ns * 16 + lane;
            const int li = ns * 16 + lane;
            const float s  = s1v[ns] + SredS[0][wn][0][li] + SredS[1][wn][0][li] + SredS[2][wn][0][li];
            const float s2 = s2v[ns] + SredS[0][wn][1][li] + SredS[1][wn][1][li] + SredS[2][wn][1][li];
            part[((size_t)blockIdx.x * 2 + 0) * N + col] = s;
            part[((size_t)blockIdx.x * 2 + 1) * N + col] = s2;
        }
    }

    // ---- C store (half select by bm; block lies wholly in one half) ----
    float* __restrict__ CO = (bm < MHALF) ? CA : CB;
    const int rsub = (bm < MHALF) ? 0 : MHALF;
#pragma unroll
    for (int ms = 0; ms < 8; ++ms)
#pragma unroll
        for (int ns = 0; ns < 2; ++ns) {
            const int row = bm - rsub + wm * 128 + ms * 16 + quad * 4;
            const int col = bn + wn * 32 + ns * 16 + r16;
#pragma unroll
            for (int r = 0; r < 4; ++r)
                CO[(size_t)(row + r) * N + col] = acc[ms][ns][r];
        }
}

// ============ f32-via-bf16x3 MFMA GEMM — merged halves + FUSED STATS ======
struct Sp3 { unsigned int o0, o1, o2; };

__device__ inline Sp3 split_pair(float x, float y)
{
    const unsigned int xb = __float_as_uint(x), yb = __float_as_uint(y);
    const unsigned int x0 = xb & 0xFFFF0000u,  y0 = yb & 0xFFFF0000u;
    const float xr1 = x - __uint_as_float(x0), yr1 = y - __uint_as_float(y0);
    const unsigned int x1b = __float_as_uint(xr1), y1b = __float_as_uint(yr1);
    const unsigned int x1 = x1b & 0xFFFF0000u, y1 = y1b & 0xFFFF0000u;
    const float xr2 = xr1 - __uint_as_float(x1), yr2 = yr1 - __uint_as_float(y1);
    Sp3 r;
    // pack bf16 pair (x in low16, y in high16) = bytes [x.b2,x.b3,y.b2,y.b3]
    r.o0 = __builtin_amdgcn_perm(yb, xb, 0x07060302u);
    r.o1 = __builtin_amdgcn_perm(y1b, x1b, 0x07060302u);
    r.o2 = __builtin_amdgcn_perm(__float_as_uint(yr2), __float_as_uint(xr2), 0x07060302u);
    return r;
}

__global__ __launch_bounds__(256) void mfma_f32x3_gemm(
    const float* __restrict__ A,            // [M,K] f32 (full M)
    const unsigned short* __restrict__ Wh,  // [N,K] bf16 planes (exact sum)
    const unsigned short* __restrict__ Wm,
    const unsigned short* __restrict__ Wl,
    float* __restrict__ CA,                 // rows [0, MHALF)
    float* __restrict__ CB,                 // rows [MHALF, M)
    float* __restrict__ part,               // [chunks][2][N]
    int M, int N, int K)
{
    __shared__ __align__(16) unsigned short Blds[2][3][128][32];  // 48 KB dbuf
    __shared__ float SredF[2][2][64];                             // 1 KB
    const int tid = threadIdx.x;
    const int wv = tid >> 6;
    const int lane = tid & 63;
    const int wm = wv >> 1, wn = wv & 1;
    const int r16 = lane & 15, quad = lane >> 4;

    // XCD-chunked panel swizzle (bijective: 8 XCDs x 32 panels x 16 N-tiles)
    const int lin = blockIdx.y * 16 + blockIdx.x;   // dispatch-order index
    const int ppx = gridDim.y >> 3;                 // M-panels per XCD (32)
    const int xcd = lin & 7, li = lin >> 3;
    const int pm = xcd * ppx + (li >> 4);           // 0..255 global M-tile
    const int pn = li & 15;
    const int bm = pm * 128;
    const int bn = pn * 128;

    f4v acc[4][4] = {};

    const int rl = lane >> 2, chl = lane & 3;
    size_t soff[2];
    int ldsrow[2];
#pragma unroll
    for (int i = 0; i < 2; ++i) {
        const int r = i * 64 + wv * 16 + rl;           // 0..127
        const int kc = (chl - (r >> 1)) & 3;
        soff[i] = (size_t)(bn + r) * K + kc * 8;       // ushort units
        ldsrow[i] = i * 64 + wv * 16;
    }

    size_t aoff[4];
#pragma unroll
    for (int ms = 0; ms < 4; ++ms)
        aoff[ms] = (size_t)(bm + wm * 64 + ms * 16 + r16) * K + quad * 8;  // f32

    int bR[4], bC[4];
#pragma unroll
    for (int ns = 0; ns < 4; ++ns) {
        bR[ns] = wn * 64 + ns * 16 + r16;
        bC[ns] = ((quad + (bR[ns] >> 1)) & 3) * 8;
    }

    auto stage = [&](int buf, int p, int i, int k0) {
        const unsigned short* Wp = (p == 0) ? Wh : (p == 1) ? Wm : Wl;
        __builtin_amdgcn_global_load_lds(
            (const __attribute__((address_space(1))) void*)(Wp + soff[i] + k0),
            (__attribute__((address_space(3))) void*)&Blds[buf][p][ldsrow[i]][0], 16, 0, 0);
    };

    float4 av[4][2];
#pragma unroll
    for (int ms = 0; ms < 4; ++ms) {
        av[ms][0] = *(const float4*)(A + aoff[ms]);
        av[ms][1] = *(const float4*)(A + aoff[ms] + 4);
    }
#pragma unroll
    for (int p = 0; p < 3; ++p)
#pragma unroll
        for (int i = 0; i < 2; ++i) stage(0, p, i, 0);
    __syncthreads();

    const int NT = K >> 5;   // BK=32
    for (int t = 0; t < NT; ++t) {
        const int cur = t & 1, nxt = cur ^ 1;
        const int k0 = t << 5;

        if (t + 1 < NT) {
#pragma unroll
            for (int p = 0; p < 3; ++p)
#pragma unroll
                for (int i = 0; i < 2; ++i) stage(nxt, p, i, k0 + 32);
        }

        s8v afr[3][4];
#pragma unroll
        for (int ms = 0; ms < 4; ++ms) {
            ABu t0, t1, t2;
            const float4 v0 = av[ms][0];
            const float4 v1 = av[ms][1];
            const Sp3 s0 = split_pair(v0.x, v0.y);
            const Sp3 s1 = split_pair(v0.z, v0.w);
            const Sp3 s2 = split_pair(v1.x, v1.y);
            const Sp3 s3 = split_pair(v1.z, v1.w);
            t0.u[0] = s0.o0; t1.u[0] = s0.o1; t2.u[0] = s0.o2;
            t0.u[1] = s1.o0; t1.u[1] = s1.o1; t2.u[1] = s1.o2;
            t0.u[2] = s2.o0; t1.u[2] = s2.o1; t2.u[2] = s2.o2;
            t0.u[3] = s3.o0; t1.u[3] = s3.o1; t2.u[3] = s3.o2;
            afr[0][ms] = t0.v;
            afr[1][ms] = t1.v;
            afr[2][ms] = t2.v;
        }
        if (t + 1 < NT) {
#pragma unroll
            for (int ms = 0; ms < 4; ++ms) {
                av[ms][0] = *(const float4*)(A + aoff[ms] + k0 + 32);
                av[ms][1] = *(const float4*)(A + aoff[ms] + k0 + 32 + 4);
            }
        }

#pragma unroll
        for (int pw = 0; pw < 3; ++pw) {
            s8v bf[4];
#pragma unroll
            for (int ns = 0; ns < 4; ++ns)
                bf[ns] = *(const s8v*)&Blds[cur][pw][bR[ns]][bC[ns]];
            __builtin_amdgcn_s_setprio(1);
#pragma unroll
            for (int pa = 0; pa + pw < 3; ++pa)
#pragma unroll
                for (int ms = 0; ms < 4; ++ms)
#pragma unroll
                    for (int ns = 0; ns < 4; ++ns)
                        acc[ms][ns] = __builtin_amdgcn_mfma_f32_16x16x32_bf16(
                            afr[pa][ms], bf[ns], acc[ms][ns], 0, 0, 0);
            __builtin_amdgcn_s_setprio(0);
        }

        if (t + 1 < NT) __syncthreads();
    }

    // ---- fused BN partial stats: per-col sums of this block's 128 rows ----
    float s1v[4], s2v[4];
#pragma unroll
    for (int ns = 0; ns < 4; ++ns) {
        float s = 0.f, s2 = 0.f;
#pragma unroll
        for (int ms = 0; ms < 4; ++ms)
#pragma unroll
            for (int r = 0; r < 4; ++r) {
                const float v = acc[ms][ns][r];
                s += v;
                s2 = fmaf(v, v, s2);
            }
        s += __shfl_down(s, 32);  s += __shfl_down(s, 16);
        s2 += __shfl_down(s2, 32); s2 += __shfl_down(s2, 16);
        s1v[ns] = s; s2v[ns] = s2;
    }
    __syncthreads();
    if (wm == 1 && lane < 16) {
#pragma unroll
        for (int ns = 0; ns < 4; ++ns) {
            SredF[wn][0][ns * 16 + lane] = s1v[ns];
            SredF[wn][1][ns * 16 + lane] = s2v[ns];
        }
    }
    __syncthreads();
    if (wm == 0 && lane < 16) {
#pragma unroll
        for (int ns = 0; ns < 4; ++ns) {
            const int col = bn + wn * 64 + ns * 16 + lane;
            const int li = ns * 16 + lane;
            part[((size_t)pm * 2 + 0) * N + col] = s1v[ns] + SredF[wn][0][li];
            part[((size_t)pm * 2 + 1) * N + col] = s2v[ns] + SredF[wn][1][li];
        }
    }

    // ---- C store (half select by bm) ----
    float* __restrict__ CO = (bm < MHALF) ? CA : CB;
    const int rsub = (bm < MHALF) ? 0 : MHALF;
#pragma unroll
    for (int ms = 0; ms < 4; ++ms)
#pragma unroll
        for (int ns = 0; ns < 4; ++ns) {
            const int row = bm - rsub + wm * 64 + ms * 16 + quad * 4;
            const int col = bn + wn * 64 + ns * 16 + r16;
#pragma unroll
            for (int r = 0; r < 4; ++r)
                CO[(size_t)(row + r) * N + col] = acc[ms][ns][r];
        }
}

// ============ BN stats finalize (partials now come from GEMM epilogues) ===
#define RCHUNK 128

__global__ void bn_stats_final(const float* __restrict__ partial,
                               float* __restrict__ stats,
                               int N, int nchunks)
{
    const int n = blockIdx.x * 256 + threadIdx.x;
    double s = 0.0, s2 = 0.0;
    for (int c = 0; c < nchunks; ++c) {
        s  += (double)partial[((size_t)c * 2 + 0) * N + n];
        s2 += (double)partial[((size_t)c * 2 + 1) * N + n];
    }
    const double inv_m = 1.0 / (double)MM;
    const double mu = s * inv_m;
    const double var = s2 * inv_m - mu * mu;
    stats[n]     = (float)mu;
    stats[N + n] = (float)(1.0 / sqrt(var + 1e-5));
}

// ============ fused BN + LIF scan — pack writes TRANSPOSED spikes =========
#define LIF_STEP_PACK(hv)                                            \
    do {                                                             \
        const float hn = ((hv) - mu) * rstd * g + bi;                \
        u = beta * (u - s) + omb * hn;                               \
        const bool sp = (u - 1.0f) >= 0.f;                           \
        s = sp ? 1.f : 0.f;                                          \
        const unsigned long long mball = __ballot(sp);               \
        if (lead) bits[widx] = mball;                                \
        ++widx;                                                      \
    } while (0)

#define LIF_LOAD8(buf, tbase)                                        \
    _Pragma("unroll")                                                \
    for (int j = 0; j < 8; ++j) {                                    \
        const int tl = (tbase) + j;                                  \
        buf[j] = h[base + (size_t)(tl < TT ? tl : TT - 1) * N];      \
    }

__global__ __launch_bounds__(64) void bn_lif_scan_pack2(
    const float* __restrict__ hA,      // [MHALF, N]  (b < 16)
    const float* __restrict__ hB,      // [MHALF, N]  (b >= 16)
    unsigned long long* __restrict__ bits,  // [N/64][MM] transposed
    const float* __restrict__ stats,
    const float* __restrict__ gamma,
    const float* __restrict__ bias,
    const float* __restrict__ beta_p,
    const float* __restrict__ U0,      // [BB, N]
    int N)
{
    const int n = blockIdx.x * 64 + threadIdx.x;
    const int b = blockIdx.y;                       // global batch 0..31
    const float* __restrict__ h = (b < BB / 2) ? hA : hB;
    const int bl = b & (BB / 2 - 1);
    const float mu = stats[n];
    const float rstd = stats[N + n];
    const float g = gamma[n];
    const float bi = bias[n];
    const float beta = 1.f / (1.f + expf(-beta_p[n]));
    const float omb = 1.f - beta;
    float u = U0[(size_t)b * N + n];
    float s = 0.f;
    const size_t base = ((size_t)bl * TT) * N + n;
    size_t widx = (size_t)(n >> 6) * (size_t)MM + (size_t)b * TT;
    const bool lead = (threadIdx.x & 63) == 0;

    float b0[8], b1[8], b2[8], b3[8];
    LIF_LOAD8(b0, 0);
    LIF_LOAD8(b1, 8);
    LIF_LOAD8(b2, 16);
    for (int t0 = 0; t0 < TT; t0 += 32) {
        LIF_LOAD8(b3, t0 + 24);
#pragma unroll
        for (int j = 0; j < 8; ++j) { const float hv = b0[j]; LIF_STEP_PACK(hv); }
        LIF_LOAD8(b0, t0 + 32);
#pragma unroll
        for (int j = 0; j < 8; ++j) { const float hv = b1[j]; LIF_STEP_PACK(hv); }
        LIF_LOAD8(b1, t0 + 40);
#pragma unroll
        for (int j = 0; j < 8; ++j) { const float hv = b2[j]; LIF_STEP_PACK(hv); }
        LIF_LOAD8(b2, t0 + 48);
#pragma unroll
        for (int j = 0; j < 8; ++j) { const float hv = b3[j]; LIF_STEP_PACK(hv); }
    }
}

#define LIF_STEP_F32(hv)                                             \
    do {                                                             \
        const float hn = ((hv) - mu) * rstd * g + bi;                \
        u = beta * (u - s) + omb * hn;                               \
        s = ((u - 1.0f) >= 0.f) ? 1.f : 0.f;                         \
        out[oidx] = s;                                               \
        oidx += N;                                                   \
    } while (0)

__global__ __launch_bounds__(64) void bn_lif_scan_f32_2(
    const float* __restrict__ h,       // [MM, N] (full)
    float* __restrict__ out,
    const float* __restrict__ stats,
    const float* __restrict__ gamma,
    const float* __restrict__ bias,
    const float* __restrict__ beta_p,
    const float* __restrict__ U0,
    int N)
{
    const int n = blockIdx.x * 64 + threadIdx.x;
    const int b = blockIdx.y;
    const float mu = stats[n];
    const float rstd = stats[N + n];
    const float g = gamma[n];
    const float bi = bias[n];
    const float beta = 1.f / (1.f + expf(-beta_p[n]));
    const float omb = 1.f - beta;
    float u = U0[(size_t)b * N + n];
    float s = 0.f;
    const size_t base = ((size_t)b * TT) * N + n;
    size_t oidx = base;

    float b0[8], b1[8], b2[8], b3[8];
    LIF_LOAD8(b0, 0);
    LIF_LOAD8(b1, 8);
    LIF_LOAD8(b2, 16);
    for (int t0 = 0; t0 < TT; t0 += 32) {
        LIF_LOAD8(b3, t0 + 24);
#pragma unroll
        for (int j = 0; j < 8; ++j) { const float hv = b0[j]; LIF_STEP_F32(hv); }
        LIF_LOAD8(b0, t0 + 32);
#pragma unroll
        for (int j = 0; j < 8; ++j) { const float hv = b1[j]; LIF_STEP_F32(hv); }
        LIF_LOAD8(b1, t0 + 40);
#pragma unroll
        for (int j = 0; j < 8; ++j) { const float hv = b2[j]; LIF_STEP_F32(hv); }
        LIF_LOAD8(b2, t0 + 48);
#pragma unroll
        for (int j = 0; j < 8; ++j) { const float hv = b3[j]; LIF_STEP_F32(hv); }
    }
}

// ============ launcher ====================================================
extern "C" void kernel_launch(void* const* d_in, const int* in_sizes, int n_in,
                              void* d_out, int out_size, void* d_ws, size_t ws_size,
                              hipStream_t stream)
{
    const float* x   = (const float*)d_in[0];
    const float* W1  = (const float*)d_in[1];
    const float* bp1 = (const float*)d_in[2];
    const float* g1  = (const float*)d_in[3];
    const float* bi1 = (const float*)d_in[4];
    const float* U01 = (const float*)d_in[5];
    const float* W2  = (const float*)d_in[6];
    const float* bp2 = (const float*)d_in[7];
    const float* g2  = (const float*)d_in[8];
    const float* bi2 = (const float*)d_in[9];
    const float* U02 = (const float*)d_in[10];
    const float* W3  = (const float*)d_in[11];
    const float* bp3 = (const float*)d_in[12];
    const float* g3  = (const float*)d_in[13];
    const float* bi3 = (const float*)d_in[14];
    const float* U03 = (const float*)d_in[15];
    float* out = (float*)d_out;

    // ws layout (unchanged, ~185 MB): hA | spk | part | stat | W2/W3 planes
    unsigned char* ws = (unsigned char*)d_ws;
    const size_t HA_BYTES  = (size_t)MHALF * HH * sizeof(float);  // 134217728
    const size_t SPK_BYTES = (size_t)MM * (HH / 8);               // 8388608
    float*              hA   = (float*)ws;
    float*              hB   = (float*)d_out;  // scratch until final scan
    unsigned long long* spk  = (unsigned long long*)(ws + HA_BYTES);
    float*              part = (float*)(ws + HA_BYTES + SPK_BYTES);
    float*              stat = (float*)(ws + HA_BYTES + SPK_BYTES + 4194304);
    unsigned short*     W2h  = (unsigned short*)(ws + HA_BYTES + SPK_BYTES + 4194304 + 16384);
    unsigned short*     W2m  = W2h + (size_t)HH * HH;
    unsigned short*     W2l  = W2m + (size_t)HH * HH;
    unsigned short*     W3h  = W2l + (size_t)HH * HH;
    unsigned short*     W3m  = W3h + (size_t)JJ * HH;
    unsigned short*     W3l  = W3m + (size_t)JJ * HH;

    const dim3 blk(256);
    const dim3 blk64(64);
    const dim3 blk512(512);

    // ---- Layer 1: x[M,J](f32) * W1[H,J]^T via 6-term bf16x3 MFMA ----
    split_w<<<dim3((HH * JJ) / 256), blk, 0, stream>>>(W1, W2h, W2m, W2l, HH * JJ);
    mfma_f32x3_gemm<<<dim3(HH / 128, MM / 128), blk, 0, stream>>>(
        x, W2h, W2m, W2l, hA, hB, part, MM, HH, JJ);
    // now W1 planes are dead — split W2/W3 into their home slots
    split_w<<<dim3((HH * HH) / 256), blk, 0, stream>>>(W2, W2h, W2m, W2l, HH * HH);
    split_w<<<dim3((JJ * HH) / 256), blk, 0, stream>>>(W3, W3h, W3m, W3l, JJ * HH);

    bn_stats_final<<<dim3(HH / 256), blk, 0, stream>>>(part, stat, HH, MM / 128);
    bn_lif_scan_pack2<<<dim3(HH / 64, BB), blk64, 0, stream>>>(
        hA, hB, spk, stat, g1, bi1, bp1, U01, HH);

    // ---- Layer 2: spk[H/64][MM] * W2[H,H]^T (merged halves, fused stats) ----
    mfma_spk_gemm<<<dim3(MM / 512, HH / 64), blk512, 0, stream>>>(
        spk, MM, W2h, W2m, W2l, hA, hB, part, MM, HH, HH);
    bn_stats_final<<<dim3(HH / 256), blk, 0, stream>>>(part, stat, HH, MM / 512);
    bn_lif_scan_pack2<<<dim3(HH / 64, BB), blk64, 0, stream>>>(
        hA, hB, spk, stat, g2, bi2, bp2, U02, HH);

    // ---- Layer 3: spk[H/64][MM] * W3[J,H]^T -> hA [M,1024] ----
    mfma_spk_gemm<<<dim3(MM / 512, JJ / 64), blk512, 0, stream>>>(
        spk, MM, W3h, W3m, W3l, hA, hA + (size_t)MHALF * JJ, part, MM, JJ, HH);
    bn_stats_final<<<dim3(JJ / 256), blk, 0, stream>>>(part, stat, JJ, MM / 512);
    bn_lif_scan_f32_2<<<dim3(JJ / 64, BB), blk64, 0, stream>>>(
        hA, out, stat, g3, bi3, bp3, U03, JJ);
}